// Round 10
// baseline (474.612 us; speedup 1.0000x reference)
//
#include <hip/hip_runtime.h>
#include <hip/hip_bf16.h>
#include <stdint.h>

#define N_TOK 4096
#define DIM   1024
#define NE    8
#define HID   4096
#define OUTD  1024
#define TOPK  2
#define SLOTS (N_TOK*TOPK)

typedef __bf16 bf16_t;
typedef __attribute__((ext_vector_type(8))) __bf16 bf16x8;
typedef __attribute__((ext_vector_type(4))) __bf16 bf16x4;
typedef __attribute__((ext_vector_type(4))) float  f32x4;

// ---------------- fused gating (fp64 logits, top-2, softmax) + x -> bf16 cast ----------------
__global__ void k_gatecast(const float* __restrict__ x, const float* __restrict__ wg,
                           bf16_t* __restrict__ xb,
                           int* __restrict__ tki, float* __restrict__ tkg,
                           int* __restrict__ counts) {
    int n = blockIdx.x;
    int lane = threadIdx.x;            // 64 threads = 1 wave
    const float* xr = x + (size_t)n * DIM;
    double acc[NE];
#pragma unroll
    for (int e = 0; e < NE; ++e) acc[e] = 0.0;
#pragma unroll
    for (int i = 0; i < 4; ++i) {
        int d0 = i * 256 + lane * 4;
        float4 v = *(const float4*)&xr[d0];
        bf16x4 o;
        o[0] = (__bf16)v.x; o[1] = (__bf16)v.y; o[2] = (__bf16)v.z; o[3] = (__bf16)v.w;
        *(bf16x4*)&xb[(size_t)n * DIM + d0] = o;
        const float* wr = wg + (size_t)d0 * NE;
#pragma unroll
        for (int j = 0; j < 4; ++j) {
            double xv = (double)((&v.x)[j]);
#pragma unroll
            for (int e = 0; e < NE; ++e) acc[e] += xv * (double)wr[j * NE + e];
        }
    }
#pragma unroll
    for (int e = 0; e < NE; ++e)
        for (int off = 32; off > 0; off >>= 1) acc[e] += __shfl_xor(acc[e], off);
    if (lane == 0) {
        int i0 = 0; double v0 = acc[0];
#pragma unroll
        for (int e = 1; e < NE; ++e) if (acc[e] > v0) { v0 = acc[e]; i0 = e; }
        int i1 = -1; double v1 = -1e300;
#pragma unroll
        for (int e = 0; e < NE; ++e) if (e != i0 && acc[e] > v1) { v1 = acc[e]; i1 = e; }
        double e1 = exp(v1 - v0);
        double s = 1.0 + e1;
        tki[n*2]   = i0;  tki[n*2+1] = i1;
        tkg[n*2]   = (float)(1.0 / s);
        tkg[n*2+1] = (float)(e1 / s);
        atomicAdd(&counts[i0], 1);
        atomicAdd(&counts[i1], 1);
    }
}

// ---------------- importance: deterministic per-expert reduction ----------------
__global__ void k_importance(const int* __restrict__ tki, const float* __restrict__ tkg,
                             float* __restrict__ imp) {
    int e = blockIdx.x, t = threadIdx.x;
    __shared__ float red[256];
    float s = 0.f;
    for (int i = t; i < SLOTS; i += 256) s += (tki[i] == e) ? tkg[i] : 0.f;
    red[t] = s; __syncthreads();
    for (int off = 128; off > 0; off >>= 1) {
        if (t < off) red[t] += red[t + off];
        __syncthreads();
    }
    if (t == 0) imp[e] = red[0];
}

// ---------------- aux loss + prefix-sum bases ----------------
__global__ void k_finalize(const float* __restrict__ imp, const int* __restrict__ counts,
                           int* __restrict__ bases, float* __restrict__ aux_out) {
    if (threadIdx.x == 0 && blockIdx.x == 0) {
        float m = 0.f;
        for (int e = 0; e < NE; ++e) m += imp[e];
        m /= (float)NE;
        float var = 0.f;
        for (int e = 0; e < NE; ++e) { float d = imp[e] - m; var += d * d; }
        var /= (float)NE;
        aux_out[0] = 0.01f * var / (m * m + 1e-10f);
        int b = 0;
        for (int e = 0; e < NE; ++e) { bases[e] = b; b += counts[e]; }
    }
}

// ---------------- build per-expert token lists + inverse slot map ----------------
__global__ void k_build(const int* __restrict__ tki,
                        const int* __restrict__ bases, int* __restrict__ cursor,
                        int* __restrict__ tok_ids, int* __restrict__ slotmap) {
    int i = blockIdx.x * 256 + threadIdx.x;
    if (i < SLOTS) {
        int e = tki[i];
        int p = atomicAdd(&cursor[e], 1);
        int s = bases[e] + p;
        tok_ids[s] = i >> 1;
        slotmap[i] = s;
    }
}

// ---------------- W [E][R][C] fp32 -> Wt [E][C][R] bf16, 64x64 tiles ----------------
__global__ void k_transpose(const float* __restrict__ src, bf16_t* __restrict__ dst,
                            int R, int C) {
    __shared__ float tile[64][65];
    const size_t slab = (size_t)R * C;
    const float* s = src + slab * blockIdx.z;
    bf16_t*      d = dst + slab * blockIdx.z;
    int c0 = blockIdx.x * 64, r0 = blockIdx.y * 64;
    int tx = threadIdx.x & 15;
    int ty = threadIdx.x >> 4;
#pragma unroll
    for (int p = 0; p < 4; ++p) {
        int rr = p * 16 + ty;
        float4 v = *(const float4*)&s[(size_t)(r0 + rr) * C + c0 + tx * 4];
        tile[rr][tx*4+0] = v.x; tile[rr][tx*4+1] = v.y;
        tile[rr][tx*4+2] = v.z; tile[rr][tx*4+3] = v.w;
    }
    __syncthreads();
    int c8 = (threadIdx.x & 7) * 8;
    int rb = threadIdx.x >> 3;
#pragma unroll
    for (int p = 0; p < 2; ++p) {
        int cc = p * 32 + rb;
        bf16x8 o;
#pragma unroll
        for (int u = 0; u < 8; ++u) o[u] = (__bf16)tile[c8 + u][cc];
        *(bf16x8*)&d[(size_t)(c0 + cc) * R + r0 + c8] = o;
    }
}

// ---------------- grouped GEMM, 128x128 tile, BK=32, 4 waves, read-ahead + occupancy-3 ----------------
// 3 LDS buffers x 16 KiB = 48 KiB static -> up to 3 blocks/CU (m114 cross-block overlap).
// Per sub-iter C (1 barrier): vmcnt(4) [C+1 landed, C+2 in flight - counted, never 0 in
// steady state] ; lgkm0 [reads(C) done, hidden under MM(C-1)] ; s_barrier ;
// STAGE(C+3 -> buf C%3, 4 GLL; reads(C) confirmed by all waves pre-barrier -> dead region] ;
// RD(C+1 -> alternate reg set, 8 b128) ; 16 MFMA(C).
// Swizzle = R1/R2 verified zero-conflict BK=32 layout: slot ^= (row>>1)&3 both-sides.
// Dense worklist: grid 2048 = 8 XCD-pinned experts x 256 slots; ti loop, y-fastest (L2).
// MODE 0: hbuf[slot] = relu(x_gather @ W1t^T + b1)
// MODE 1 (KSPLIT=4): ybuf[kslot][slot] = h @ W2t^T (+b2 on kslot 0), combined later.
template <int MODE>
__global__ __launch_bounds__(256)
void k_gemm(const bf16_t* __restrict__ A,    // MODE0: xb [N][DIM]; MODE1: hbuf [SLOTS][HID]
            const bf16_t* __restrict__ Bt,   // MODE0: w1t [E][HID][DIM]; MODE1: w2t [E][OUTD][HID]
            const float* __restrict__ bias,
            const int* __restrict__ tok_ids,
            const int* __restrict__ bases,
            const int* __restrict__ counts,
            bf16_t* __restrict__ Y) {
    constexpr int KD   = (MODE == 0) ? DIM : HID;
    constexpr int ND   = (MODE == 0) ? HID : OUTD;
    constexpr int NPAN = ND / 128;            // 32 / 8
    constexpr int KT   = 32;                  // KLEN = 1024 both modes (MODE1: KSPLIT=4)

    const int e  = blockIdx.x & 7;            // expert pinned to XCD
    const int lb = blockIdx.x >> 3;           // 0..255
    const int ne = counts[e];
    if (ne == 0) return;
    const int b0 = bases[e];
    const int NTy = (ne + 127) >> 7;
    const int NTILES = NPAN * NTy * ((MODE == 0) ? 1 : 4);

    __shared__ bf16_t lds[24576];             // A bufs @ b*4096 ; B bufs @ 12288 + b*4096

    const int t = threadIdx.x, w = t >> 6, L = t & 63;
    const int wm = w >> 1, wn = w & 1;        // 2x2 waves; per-wave out 64x64
    const int lr = L & 15, lq = L >> 4;
    const int half  = w & 1;                  // staging half (A: waves 0-1, B: waves 2-3)
    const int srow  = L >> 2;                 // row within 16-row group
    const int sslot = L & 3;                  // 16B slot

    // fragment read offsets (elems within one 4096-elem buffer; B adds 12288 base)
    int offA[4], offB[4];
#pragma unroll
    for (int i = 0; i < 4; ++i) {
        int r = wm * 64 + i * 16 + lr;
        offA[i] = r * 32 + ((lq ^ ((r >> 1) & 3)) << 3);
    }
#pragma unroll
    for (int j = 0; j < 4; ++j) {
        int r = wn * 64 + j * 16 + lr;
        offB[j] = 12288 + r * 32 + ((lq ^ ((r >> 1) & 3)) << 3);
    }
    // wave-uniform LDS stage bases (elems)
    int sdst[4];
#pragma unroll
    for (int p = 0; p < 4; ++p)
        sdst[p] = (w >= 2 ? 12288 : 0) + (half * 64 + p * 16) * 32;

#define GLL(srcp, dste) __builtin_amdgcn_global_load_lds( \
        (const __attribute__((address_space(1))) uint32_t*)(srcp), \
        (__attribute__((address_space(3))) uint32_t*)(lds + (dste)), 16, 0, 0)
#define STAGE(Tt, bsl) { \
        _Pragma("unroll") for (int p_ = 0; p_ < 4; ++p_) \
            GLL(gsrc[p_] + (Tt) * 32, sdst[p_] + (bsl) * 4096); }
#define RD(FA, FB, bsl) { \
        _Pragma("unroll") for (int i_ = 0; i_ < 4; ++i_) \
            FA[i_] = *(const bf16x8*)(lds + (bsl) * 4096 + offA[i_]); \
        _Pragma("unroll") for (int j_ = 0; j_ < 4; ++j_) \
            FB[j_] = *(const bf16x8*)(lds + (bsl) * 4096 + offB[j_]); }
#define MM(FA, FB) { \
        __builtin_amdgcn_s_setprio(1); \
        _Pragma("unroll") for (int i_ = 0; i_ < 4; ++i_) \
        _Pragma("unroll") for (int j_ = 0; j_ < 4; ++j_) \
            acc[i_][j_] = __builtin_amdgcn_mfma_f32_16x16x32_bf16(FB[j_], FA[i_], acc[i_][j_], 0, 0, 0); \
        __builtin_amdgcn_s_setprio(0); }
#define SUB(C, FcA, FcB, FnA, FnB) { \
        if ((C) + 2 < KT) { asm volatile("s_waitcnt vmcnt(4)" ::: "memory"); } \
        else              { asm volatile("s_waitcnt vmcnt(0)" ::: "memory"); } \
        asm volatile("s_waitcnt lgkmcnt(0)" ::: "memory"); \
        __builtin_amdgcn_sched_barrier(0); \
        __builtin_amdgcn_s_barrier(); \
        if ((C) + 3 < KT) STAGE((C) + 3, ((C) + 3) % 3); \
        if ((C) + 1 < KT) RD(FnA, FnB, ((C) + 1) % 3); \
        __builtin_amdgcn_sched_barrier(0); \
        MM(FcA, FcB); }

    for (int ti = lb; ti < NTILES; ti += 256) {
        int panel, y, kslot;
        if (MODE == 0) { panel = ti / NTy; y = ti - panel * NTy; kslot = 0; }
        else { int u = ti / NTy; y = ti - u * NTy; kslot = u >> 3; panel = u & 7; }
        const int m0 = y * 128, n0 = panel * 128;
        const int koff = (MODE == 0) ? 0 : kslot * 1024;
        bf16_t* __restrict__ Yw = (MODE == 0) ? Y : (Y + (size_t)kslot * SLOTS * OUTD);

        // global stage pointers (A for waves 0-1, B for waves 2-3)
        const bf16_t* gsrc[4];
#pragma unroll
        for (int p = 0; p < 4; ++p) {
            int row = half * 64 + p * 16 + srow;
            int gk  = sslot ^ ((row >> 1) & 3);
            if (w < 2) {
                int mm = m0 + row;
                int rr = (mm < ne) ? mm : (ne - 1);
                size_t arow = (MODE == 0) ? (size_t)tok_ids[b0 + rr] * KD
                                          : (size_t)(b0 + rr) * KD;
                gsrc[p] = A + arow + koff + gk * 8;
            } else {
                gsrc[p] = Bt + ((size_t)e * ND + n0 + row) * KD + koff + gk * 8;
            }
        }

        f32x4 acc[4][4];
#pragma unroll
        for (int i = 0; i < 4; ++i)
#pragma unroll
            for (int j = 0; j < 4; ++j) acc[i][j] = (f32x4){0.f, 0.f, 0.f, 0.f};

        bf16x8 fA0[4], fB0[4], fA1[4], fB1[4];

        // prologue: stage tiles 0,1,2 (12 GLL/wave); wait tile 0; read tile 0 -> set0
        STAGE(0, 0); STAGE(1, 1); STAGE(2, 2);
        asm volatile("s_waitcnt vmcnt(8)" ::: "memory");
        __builtin_amdgcn_s_barrier();
        RD(fA0, fB0, 0);

#pragma unroll
        for (int c = 0; c < KT; c += 2) {
            SUB(c,     fA0, fB0, fA1, fB1);
            SUB(c + 1, fA1, fB1, fA0, fB0);
        }

        // ---------------- epilogue: bf16 store ----------------
        const int kbias = (MODE == 0) ? 1 : (kslot == 0 ? 1 : 0);
#pragma unroll
        for (int i = 0; i < 4; ++i) {
            int gm = m0 + wm * 64 + i * 16 + lr;
            if (gm < ne) {
#pragma unroll
                for (int j = 0; j < 4; ++j) {
                    int gn = n0 + wn * 64 + j * 16 + lq * 4;
                    f32x4 bv = *(const f32x4*)&bias[(size_t)e * ND + gn];
                    bf16x4 hv;
#pragma unroll
                    for (int r = 0; r < 4; ++r) {
                        float v = acc[i][j][r];
                        if (kbias) v += bv[r];
                        if (MODE == 0) v = fmaxf(v, 0.f);
                        hv[r] = (__bf16)v;
                    }
                    *(bf16x4*)&Yw[(size_t)(b0 + gm) * ND + gn] = hv;
                }
            }
        }
    }
#undef SUB
#undef MM
#undef RD
#undef STAGE
#undef GLL
}

// ---------------- combine: out[n] = g0*sum_s y[s][slot0] + g1*sum_s y[s][slot1] ----------------
__global__ void k_combine(const bf16_t* __restrict__ ybuf,   // [4][SLOTS][OUTD]
                          const int* __restrict__ slotmap,
                          const float* __restrict__ tkg,
                          float* __restrict__ out) {
    int n = blockIdx.x;
    int d = threadIdx.x * 4;
    int s0 = slotmap[2 * n], s1 = slotmap[2 * n + 1];
    float g0 = tkg[2 * n],  g1 = tkg[2 * n + 1];
    f32x4 o = (f32x4){0.f, 0.f, 0.f, 0.f};
#pragma unroll
    for (int s = 0; s < 4; ++s) {
        const bf16_t* ys = ybuf + (size_t)s * SLOTS * OUTD;
        bf16x4 u = *(const bf16x4*)&ys[(size_t)s0 * OUTD + d];
        bf16x4 v = *(const bf16x4*)&ys[(size_t)s1 * OUTD + d];
#pragma unroll
        for (int r = 0; r < 4; ++r)
            o[r] += g0 * (float)u[r] + g1 * (float)v[r];
    }
    *(f32x4*)&out[(size_t)n * OUTD + d] = o;
}

extern "C" void kernel_launch(void* const* d_in, const int* in_sizes, int n_in,
                              void* d_out, int out_size, void* d_ws, size_t ws_size,
                              hipStream_t stream) {
    const float* x  = (const float*)d_in[0];
    const float* wg = (const float*)d_in[1];
    const float* w1 = (const float*)d_in[2];
    const float* b1 = (const float*)d_in[3];
    const float* w2 = (const float*)d_in[4];
    const float* b2 = (const float*)d_in[5];
    float* out = (float*)d_out;

    char* ws = (char*)d_ws;
    size_t o = 0;
    auto alloc = [&](size_t b) { size_t r = o; o = (o + b + 255) & ~(size_t)255; return r; };
    int*    counts  = (int*)(ws + alloc(NE * 4));
    int*    cursor  = (int*)(ws + alloc(NE * 4));
    int*    bases   = (int*)(ws + alloc(NE * 4));
    float*  imp     = (float*)(ws + alloc(NE * 4));
    int*    tki     = (int*)(ws + alloc(SLOTS * 4));
    float*  tkg     = (float*)(ws + alloc(SLOTS * 4));
    int*    tok_ids = (int*)(ws + alloc(SLOTS * 4));
    int*    slotmap = (int*)(ws + alloc(SLOTS * 4));
    bf16_t* xb      = (bf16_t*)(ws + alloc((size_t)N_TOK * DIM * 2));
    size_t  w1t_off = alloc((size_t)NE * HID * DIM * 2);
    bf16_t* w1t     = (bf16_t*)(ws + w1t_off);
    bf16_t* ybuf    = (bf16_t*)(ws + w1t_off);   // [4][SLOTS][OUTD] = exactly w1t size (dead after GEMM-1)
    bf16_t* w2t     = (bf16_t*)(ws + alloc((size_t)NE * OUTD * HID * 2));
    bf16_t* hbuf    = (bf16_t*)(ws + alloc((size_t)SLOTS * HID * 2));
    (void)ws_size; (void)n_in; (void)in_sizes;

    hipMemsetAsync(ws, 0, 1024, stream);   // counts + cursor

    k_gatecast<<<N_TOK, 64, 0, stream>>>(x, wg, xb, tki, tkg, counts);
    k_transpose<<<dim3(HID / 64, DIM / 64, NE), 256, 0, stream>>>(w1, w1t, DIM, HID);
    k_transpose<<<dim3(OUTD / 64, HID / 64, NE), 256, 0, stream>>>(w2, w2t, HID, OUTD);
    k_importance<<<NE, 256, 0, stream>>>(tki, tkg, imp);
    k_finalize<<<1, 64, 0, stream>>>(imp, counts, bases, out + (size_t)N_TOK * OUTD);
    k_build<<<SLOTS / 256, 256, 0, stream>>>(tki, bases, cursor, tok_ids, slotmap);

    // 2048 blocks = 8 XCD-pinned experts x 256 worklist slots; static 48 KiB LDS
    k_gemm<0><<<2048, 256, 0, stream>>>(xb, w1t, b1, tok_ids, bases, counts, hbuf);
    k_gemm<1><<<2048, 256, 0, stream>>>(hbuf, w2t, b2, tok_ids, bases, counts, ybuf);

    k_combine<<<N_TOK, 256, 0, stream>>>(ybuf, slotmap, tkg, out);
}

// Round 12
// 447.354 us; speedup vs baseline: 1.0609x; 1.0609x over previous
//
#include <hip/hip_runtime.h>
#include <hip/hip_bf16.h>
#include <stdint.h>

#define N_TOK 4096
#define DIM   1024
#define NE    8
#define HID   4096
#define OUTD  1024
#define TOPK  2
#define SLOTS (N_TOK*TOPK)

typedef __bf16 bf16_t;
typedef __attribute__((ext_vector_type(8))) __bf16 bf16x8;
typedef __attribute__((ext_vector_type(4))) __bf16 bf16x4;
typedef __attribute__((ext_vector_type(4))) float  f32x4;

// ================= mega prep: w1 transpose | w2 transpose | gating+cast =================
__device__ __forceinline__ void transpose_tile(const float* __restrict__ src,
                                               bf16_t* __restrict__ dst,
                                               int R, int C, int cx, int ry,
                                               float (*tile)[65]) {
    const float* s = src;
    bf16_t* d = dst;
    int c0 = cx * 64, r0 = ry * 64;
    int tx = threadIdx.x & 15;
    int ty = threadIdx.x >> 4;
#pragma unroll
    for (int p = 0; p < 4; ++p) {
        int rr = p * 16 + ty;
        float4 v = *(const float4*)&s[(size_t)(r0 + rr) * C + c0 + tx * 4];
        tile[rr][tx*4+0] = v.x; tile[rr][tx*4+1] = v.y;
        tile[rr][tx*4+2] = v.z; tile[rr][tx*4+3] = v.w;
    }
    __syncthreads();
    int c8 = (threadIdx.x & 7) * 8;
    int rb = threadIdx.x >> 3;
#pragma unroll
    for (int p = 0; p < 2; ++p) {
        int cc = p * 32 + rb;
        bf16x8 o;
#pragma unroll
        for (int u = 0; u < 8; ++u) o[u] = (__bf16)tile[c8 + u][cc];
        *(bf16x8*)&d[(size_t)(c0 + cc) * R + r0 + c8] = o;
    }
}

__global__ void k_prep(const float* __restrict__ x,  const float* __restrict__ wg,
                       const float* __restrict__ w1, const float* __restrict__ w2,
                       bf16_t* __restrict__ xb, bf16_t* __restrict__ w1t, bf16_t* __restrict__ w2t,
                       int* __restrict__ tki, float* __restrict__ tkg,
                       int* __restrict__ counts, float* __restrict__ imp) {
    __shared__ float tile[64][65];
    const int bx = blockIdx.x;
    if (bx < 8192) {                       // w1: [8][1024][4096] -> [8][4096][1024]
        int e = bx >> 10, rem = bx & 1023;
        transpose_tile(w1 + (size_t)e * DIM * HID, w1t + (size_t)e * DIM * HID,
                       DIM, HID, rem & 63, rem >> 6, tile);
        return;
    }
    if (bx < 16384) {                      // w2: [8][4096][1024] -> [8][1024][4096]
        int b2 = bx - 8192;
        int e = b2 >> 10, rem = b2 & 1023;
        transpose_tile(w2 + (size_t)e * HID * OUTD, w2t + (size_t)e * HID * OUTD,
                       HID, OUTD, rem & 15, rem >> 4, tile);
        return;
    }
    // gating: 4 waves = 4 tokens per block
    int n = (bx - 16384) * 4 + (threadIdx.x >> 6);
    int lane = threadIdx.x & 63;
    const float* xr = x + (size_t)n * DIM;
    double acc[NE];
#pragma unroll
    for (int e = 0; e < NE; ++e) acc[e] = 0.0;
#pragma unroll
    for (int i = 0; i < 4; ++i) {
        int d0 = i * 256 + lane * 4;
        float4 v = *(const float4*)&xr[d0];
        bf16x4 o;
        o[0] = (__bf16)v.x; o[1] = (__bf16)v.y; o[2] = (__bf16)v.z; o[3] = (__bf16)v.w;
        *(bf16x4*)&xb[(size_t)n * DIM + d0] = o;
        const float* wr = wg + (size_t)d0 * NE;
#pragma unroll
        for (int j = 0; j < 4; ++j) {
            double xv = (double)((&v.x)[j]);
#pragma unroll
            for (int e = 0; e < NE; ++e) acc[e] += xv * (double)wr[j * NE + e];
        }
    }
#pragma unroll
    for (int e = 0; e < NE; ++e)
        for (int off = 32; off > 0; off >>= 1) acc[e] += __shfl_xor(acc[e], off);
    if (lane == 0) {
        int i0 = 0; double v0 = acc[0];
#pragma unroll
        for (int e = 1; e < NE; ++e) if (acc[e] > v0) { v0 = acc[e]; i0 = e; }
        int i1 = -1; double v1 = -1e300;
#pragma unroll
        for (int e = 0; e < NE; ++e) if (e != i0 && acc[e] > v1) { v1 = acc[e]; i1 = e; }
        double e1 = exp(v1 - v0);
        double s = 1.0 + e1;
        float g0 = (float)(1.0 / s), g1 = (float)(e1 / s);
        tki[n*2]   = i0;  tki[n*2+1] = i1;
        tkg[n*2]   = g0;  tkg[n*2+1] = g1;
        atomicAdd(&counts[i0], 1);
        atomicAdd(&counts[i1], 1);
        atomicAdd(&imp[i0], g0);
        atomicAdd(&imp[i1], g1);
    }
}

// ---------------- aux loss + prefix-sum bases ----------------
__global__ void k_finalize(const float* __restrict__ imp, const int* __restrict__ counts,
                           int* __restrict__ bases, float* __restrict__ aux_out) {
    if (threadIdx.x == 0 && blockIdx.x == 0) {
        float m = 0.f;
        for (int e = 0; e < NE; ++e) m += imp[e];
        m /= (float)NE;
        float var = 0.f;
        for (int e = 0; e < NE; ++e) { float d = imp[e] - m; var += d * d; }
        var /= (float)NE;
        aux_out[0] = 0.01f * var / (m * m + 1e-10f);
        int b = 0;
        for (int e = 0; e < NE; ++e) { bases[e] = b; b += counts[e]; }
    }
}

// ---------------- build per-expert token lists + inverse slot map ----------------
__global__ void k_build(const int* __restrict__ tki,
                        const int* __restrict__ bases, int* __restrict__ cursor,
                        int* __restrict__ tok_ids, int* __restrict__ slotmap) {
    int i = blockIdx.x * 256 + threadIdx.x;
    if (i < SLOTS) {
        int e = tki[i];
        int p = atomicAdd(&cursor[e], 1);
        int s = bases[e] + p;
        tok_ids[s] = i >> 1;
        slotmap[i] = s;
    }
}

// ====== grouped GEMM, 256x256 tile, BK=32, 8 waves (2M x 4N), per-wave 128x64 ======
// Counted read-ahead (R9 schedule) on low-duplication geometry. 3 buffers (96 KiB).
// Per K-tile T (ONE barrier): vmcnt(4) [T landed; T+1 in flight] ; s_barrier
// [all waves' T-1 reads lgkm-retired pre-barrier -> buf (T+2)%3 free] ; stage T+2 ;
// rd fb+fa0-3 ; rd fa4-7 ; lgkm(4) -> MFMA mh0 ; lgkm(0) -> MFMA mh1.
// R12 FIXES: (1) KT = KLEN/32 per mode (R11 dropped half of MODE1's K-sum);
// (2) s_barrier before each tile's prologue staging (tile-boundary LDS race: R11's
// last-iteration reads had no covering barrier before the next tile's STAGE).
// MODE 0: hbuf[slot] = relu(x_gather @ W1t^T + b1)
// MODE 1 (KSPLIT=2): ybuf[kslot][slot] = h @ W2t^T (+b2 on kslot 0)
template <int MODE>
__global__ __launch_bounds__(512, 2)
void k_gemm(const bf16_t* __restrict__ A,    // MODE0: xb [N][DIM]; MODE1: hbuf [SLOTS][HID]
            const bf16_t* __restrict__ Bt,   // MODE0: w1t [E][HID][DIM]; MODE1: w2t [E][OUTD][HID]
            const float* __restrict__ bias,
            const int* __restrict__ tok_ids,
            const int* __restrict__ bases,
            const int* __restrict__ counts,
            bf16_t* __restrict__ Y) {
    constexpr int KD   = (MODE == 0) ? DIM : HID;
    constexpr int ND   = (MODE == 0) ? HID : OUTD;
    constexpr int KLEN = (MODE == 0) ? DIM : (HID / 2);   // 1024 / 2048
    constexpr int KT   = KLEN / 32;                       // 32 / 64   (R11 bug: was 32 fixed)
    constexpr int BUFE = 16384;               // elems per buffer (A 8192 + B 8192 = 32 KiB)

    const int e  = blockIdx.x & 7;            // expert pinned to XCD
    const int lb = blockIdx.x >> 3;           // 0..31
    const int ne = counts[e];
    if (ne == 0) return;
    const int b0 = bases[e];
    const int NTy = (ne + 255) >> 8;
    const int NTILES = (MODE == 0) ? (16 * NTy) : (8 * NTy);

    extern __shared__ bf16_t lds[];           // 3 * BUFE elems = 96 KiB

    const int t = threadIdx.x, w = t >> 6, L = t & 63;
    const int wm = w >> 2, wn = w & 3;        // 2M x 4N; per-wave out 128x64
    const int lr = L & 15, lq = L >> 4;
    const int srow  = L >> 2;                 // staging row-local (16 rows per GLL)
    const int sslot = L & 3;                  // 16B chunk

    // fragment read offsets (elems within buffer; verified zero-conflict swizzle)
    int offA[8], offB[4];
#pragma unroll
    for (int i = 0; i < 8; ++i) {
        int r = wm * 128 + i * 16 + lr;
        offA[i] = r * 32 + ((lq ^ ((r >> 1) & 3)) << 3);
    }
#pragma unroll
    for (int j = 0; j < 4; ++j) {
        int r = wn * 64 + j * 16 + lr;
        offB[j] = 8192 + r * 32 + ((lq ^ ((r >> 1) & 3)) << 3);
    }
    // wave-uniform LDS stage bases (elems): A instr g rows g*128 + w*16 ..+15
    int sdstA[2], sdstB[2];
#pragma unroll
    for (int g = 0; g < 2; ++g) {
        sdstA[g] = (g * 128 + w * 16) * 32;
        sdstB[g] = 8192 + (g * 128 + w * 16) * 32;
    }

#define GLL(srcp, dste) __builtin_amdgcn_global_load_lds( \
        (const __attribute__((address_space(1))) uint32_t*)(srcp), \
        (__attribute__((address_space(3))) uint32_t*)(lds + (dste)), 16, 0, 0)
#define STAGE(Tt, bsl) { \
        _Pragma("unroll") for (int g_ = 0; g_ < 2; ++g_) { \
            GLL(aptr[g_] + (Tt) * 32, (bsl) * BUFE + sdstA[g_]); \
            GLL(bptr[g_] + (Tt) * 32, (bsl) * BUFE + sdstB[g_]); } }

    for (int ti = lb; ti < NTILES; ti += 32) {
        int panel = ti / NTy, y = ti - panel * NTy, kslot = 0;
        if (MODE == 1) { kslot = panel & 1; panel >>= 1; }
        const int m0 = y * 256, n0 = panel * 256;
        const int koff = (MODE == 0) ? 0 : kslot * KLEN;
        bf16_t* __restrict__ Yw = (MODE == 0) ? Y : (Y + (size_t)kslot * SLOTS * OUTD);

        // global stage pointers (per GLL-instr g)
        const bf16_t* aptr[2];
        const bf16_t* bptr[2];
#pragma unroll
        for (int g = 0; g < 2; ++g) {
            int row = g * 128 + w * 16 + srow;
            int gk  = sslot ^ ((row >> 1) & 3);
            int mm = m0 + row;
            int rr = (mm < ne) ? mm : (ne - 1);
            size_t arow = (MODE == 0) ? (size_t)tok_ids[b0 + rr] * KD : (size_t)(b0 + rr) * KD;
            aptr[g] = A + arow + koff + gk * 8;
            bptr[g] = Bt + ((size_t)e * ND + n0 + row) * KD + koff + gk * 8;
        }

        f32x4 acc[8][4];
#pragma unroll
        for (int i = 0; i < 8; ++i)
#pragma unroll
            for (int j = 0; j < 4; ++j) acc[i][j] = (f32x4){0.f, 0.f, 0.f, 0.f};

        // R12 FIX (2): cover last iteration's LDS reads of the previous tile before
        // overwriting buf0/buf1 (each wave's reads are lgkm-retired in program order).
        __builtin_amdgcn_s_barrier();

        // prologue: stage tiles 0,1 (8 GLL/wave); waits happen at loop top
        STAGE(0, 0); STAGE(1, 1);

        int cb = 0;                 // T % 3
        int nb = 2;                 // (T+2) % 3
        for (int T = 0; T < KT; ++T) {
            if (T < KT - 1) { asm volatile("s_waitcnt vmcnt(4)" ::: "memory"); }
            else            { asm volatile("s_waitcnt vmcnt(0)" ::: "memory"); }
            __builtin_amdgcn_s_barrier();
            if (T + 2 < KT) STAGE(T + 2, nb);

            bf16x8 fb[4], fa[8];
#pragma unroll
            for (int j = 0; j < 4; ++j) fb[j] = *(const bf16x8*)(lds + cb * BUFE + offB[j]);
#pragma unroll
            for (int i = 0; i < 4; ++i) fa[i] = *(const bf16x8*)(lds + cb * BUFE + offA[i]);
            __builtin_amdgcn_sched_barrier(0);
#pragma unroll
            for (int i = 4; i < 8; ++i) fa[i] = *(const bf16x8*)(lds + cb * BUFE + offA[i]);
            __builtin_amdgcn_sched_barrier(0);
            asm volatile("s_waitcnt lgkmcnt(4)" ::: "memory");   // fb + fa0-3 done
            __builtin_amdgcn_sched_barrier(0);
            __builtin_amdgcn_s_setprio(1);
#pragma unroll
            for (int i = 0; i < 4; ++i)
#pragma unroll
                for (int j = 0; j < 4; ++j)
                    acc[i][j] = __builtin_amdgcn_mfma_f32_16x16x32_bf16(fb[j], fa[i], acc[i][j], 0, 0, 0);
            __builtin_amdgcn_s_setprio(0);
            asm volatile("s_waitcnt lgkmcnt(0)" ::: "memory");   // fa4-7 done (hidden under mh0)
            __builtin_amdgcn_sched_barrier(0);
            __builtin_amdgcn_s_setprio(1);
#pragma unroll
            for (int i = 4; i < 8; ++i)
#pragma unroll
                for (int j = 0; j < 4; ++j)
                    acc[i][j] = __builtin_amdgcn_mfma_f32_16x16x32_bf16(fb[j], fa[i], acc[i][j], 0, 0, 0);
            __builtin_amdgcn_s_setprio(0);

            cb = (cb == 2) ? 0 : cb + 1;
            nb = (nb == 2) ? 0 : nb + 1;
        }

        // ---------------- epilogue: bf16 store ----------------
        const int kbias = (MODE == 0) ? 1 : (kslot == 0 ? 1 : 0);
#pragma unroll
        for (int i = 0; i < 8; ++i) {
            int gm = m0 + wm * 128 + i * 16 + lr;
            if (gm < ne) {
#pragma unroll
                for (int j = 0; j < 4; ++j) {
                    int gn = n0 + wn * 64 + j * 16 + lq * 4;
                    f32x4 bv = *(const f32x4*)&bias[(size_t)e * ND + gn];
                    bf16x4 hv;
#pragma unroll
                    for (int r = 0; r < 4; ++r) {
                        float v = acc[i][j][r];
                        if (kbias) v += bv[r];
                        if (MODE == 0) v = fmaxf(v, 0.f);
                        hv[r] = (__bf16)v;
                    }
                    *(bf16x4*)&Yw[(size_t)(b0 + gm) * ND + gn] = hv;
                }
            }
        }
    }
#undef STAGE
#undef GLL
}

// ---------------- combine: out[n] = g0*(y0a+y0b) + g1*(y1a+y1b) (fp32) ----------------
__global__ void k_combine(const bf16_t* __restrict__ ybuf,   // [2][SLOTS][OUTD]
                          const int* __restrict__ slotmap,
                          const float* __restrict__ tkg,
                          float* __restrict__ out) {
    int n = blockIdx.x;
    int d = threadIdx.x * 4;
    int s0 = slotmap[2 * n], s1 = slotmap[2 * n + 1];
    float g0 = tkg[2 * n],  g1 = tkg[2 * n + 1];
    const bf16_t* y2 = ybuf + (size_t)SLOTS * OUTD;
    bf16x4 a0 = *(const bf16x4*)&ybuf[(size_t)s0 * OUTD + d];
    bf16x4 a1 = *(const bf16x4*)&y2  [(size_t)s0 * OUTD + d];
    bf16x4 c0 = *(const bf16x4*)&ybuf[(size_t)s1 * OUTD + d];
    bf16x4 c1 = *(const bf16x4*)&y2  [(size_t)s1 * OUTD + d];
    f32x4 o;
#pragma unroll
    for (int r = 0; r < 4; ++r)
        o[r] = g0 * ((float)a0[r] + (float)a1[r]) + g1 * ((float)c0[r] + (float)c1[r]);
    *(f32x4*)&out[(size_t)n * OUTD + d] = o;
}

extern "C" void kernel_launch(void* const* d_in, const int* in_sizes, int n_in,
                              void* d_out, int out_size, void* d_ws, size_t ws_size,
                              hipStream_t stream) {
    const float* x  = (const float*)d_in[0];
    const float* wg = (const float*)d_in[1];
    const float* w1 = (const float*)d_in[2];
    const float* b1 = (const float*)d_in[3];
    const float* w2 = (const float*)d_in[4];
    const float* b2 = (const float*)d_in[5];
    float* out = (float*)d_out;

    char* ws = (char*)d_ws;
    size_t o = 0;
    auto alloc = [&](size_t b) { size_t r = o; o = (o + b + 255) & ~(size_t)255; return r; };
    int*    counts  = (int*)(ws + alloc(NE * 4));
    int*    cursor  = (int*)(ws + alloc(NE * 4));
    int*    bases   = (int*)(ws + alloc(NE * 4));
    float*  imp     = (float*)(ws + alloc(NE * 4));
    int*    tki     = (int*)(ws + alloc(SLOTS * 4));
    float*  tkg     = (float*)(ws + alloc(SLOTS * 4));
    int*    tok_ids = (int*)(ws + alloc(SLOTS * 4));
    int*    slotmap = (int*)(ws + alloc(SLOTS * 4));
    bf16_t* xb      = (bf16_t*)(ws + alloc((size_t)N_TOK * DIM * 2));
    size_t  w1t_off = alloc((size_t)NE * HID * DIM * 2);
    bf16_t* w1t     = (bf16_t*)(ws + w1t_off);
    bf16_t* ybuf    = (bf16_t*)(ws + w1t_off);   // [2][SLOTS][OUTD] aliases w1t (dead after GEMM-1)
    bf16_t* w2t     = (bf16_t*)(ws + alloc((size_t)NE * OUTD * HID * 2));
    bf16_t* hbuf    = (bf16_t*)(ws + alloc((size_t)SLOTS * HID * 2));
    (void)ws_size; (void)n_in; (void)in_sizes;

    hipFuncSetAttribute((const void*)&k_gemm<0>, hipFuncAttributeMaxDynamicSharedMemorySize, 98304);
    hipFuncSetAttribute((const void*)&k_gemm<1>, hipFuncAttributeMaxDynamicSharedMemorySize, 98304);

    hipMemsetAsync(ws, 0, 1024, stream);   // counts + cursor + bases + imp

    // mega prep: 8192 w1-T + 8192 w2-T + 1024 gating blocks
    k_prep<<<16384 + 1024, 256, 0, stream>>>(x, wg, w1, w2, xb, w1t, w2t,
                                             tki, tkg, counts, imp);
    k_finalize<<<1, 64, 0, stream>>>(imp, counts, bases, out + (size_t)N_TOK * OUTD);
    k_build<<<SLOTS / 256, 256, 0, stream>>>(tki, bases, cursor, tok_ids, slotmap);

    // 256 blocks = 8 XCD-pinned experts x 32 worklist slots; 96 KiB dynamic LDS
    k_gemm<0><<<256, 512, 98304, stream>>>(xb, w1t, b1, tok_ids, bases, counts, hbuf);
    k_gemm<1><<<256, 512, 98304, stream>>>(hbuf, w2t, b2, tok_ids, bases, counts, ybuf);

    k_combine<<<N_TOK, 256, 0, stream>>>(ybuf, slotmap, tkg, out);
}

// Round 13
// 442.722 us; speedup vs baseline: 1.0720x; 1.0105x over previous
//
#include <hip/hip_runtime.h>
#include <hip/hip_bf16.h>
#include <stdint.h>

#define N_TOK 4096
#define DIM   1024
#define NE    8
#define HID   4096
#define OUTD  1024
#define TOPK  2
#define SLOTS (N_TOK*TOPK)

typedef __bf16 bf16_t;
typedef __attribute__((ext_vector_type(8))) __bf16 bf16x8;
typedef __attribute__((ext_vector_type(4))) __bf16 bf16x4;
typedef __attribute__((ext_vector_type(4))) float  f32x4;

// ================= mega prep: w1 transpose | w2 transpose | gating+cast =================
// R13 transpose: 256(src-rows) x 64(src-cols) tiles, 512 thr, bf16-early LDS [256][66]
// (odd-dword stride: write side conflict-free, read side <=4-way). Writes: 8 lanes x 16B
// = 128B contiguous per out-row, q-loop extends to 512B. Reads: consecutive-cx blocks
// collectively cover full 16KB src rows. Fixes R12's 128B-stride-2KB write thrash (1.3 TB/s).
__global__ __launch_bounds__(512)
void k_prep(const float* __restrict__ x,  const float* __restrict__ wg,
            const float* __restrict__ w1, const float* __restrict__ w2,
            bf16_t* __restrict__ xb, bf16_t* __restrict__ w1t, bf16_t* __restrict__ w2t,
            int* __restrict__ tki, float* __restrict__ tkg,
            int* __restrict__ counts, float* __restrict__ imp) {
    __shared__ bf16_t tile[256][66];      // 33.8 KB
    const int bx = blockIdx.x;
    const int t  = threadIdx.x;
    if (bx < 4096) {
        const float* src; bf16_t* dst; int R, C, ry, cx;
        if (bx < 2048) {                  // w1: [8][1024][4096] -> [8][4096][1024]
            int e = bx >> 8, rem = bx & 255;
            ry = rem >> 6; cx = rem & 63;
            src = w1 + (size_t)e * DIM * HID; dst = w1t + (size_t)e * DIM * HID;
            R = DIM; C = HID;
        } else {                          // w2: [8][4096][1024] -> [8][1024][4096]
            int b2 = bx - 2048;
            int e = b2 >> 8, rem = b2 & 255;
            ry = rem >> 4; cx = rem & 15;
            src = w2 + (size_t)e * HID * OUTD; dst = w2t + (size_t)e * HID * OUTD;
            R = HID; C = OUTD;
        }
        const int r0 = ry * 256, c0 = cx * 64;
        const int tx = t & 15, tr = t >> 4;   // 16 col-quads x 32 row-groups
#pragma unroll
        for (int p = 0; p < 8; ++p) {
            int r = tr + p * 32;
            float4 v = *(const float4*)&src[(size_t)(r0 + r) * C + c0 + tx * 4];
            bf16x4 o;
            o[0] = (__bf16)v.x; o[1] = (__bf16)v.y; o[2] = (__bf16)v.z; o[3] = (__bf16)v.w;
            *(bf16x4*)&tile[r][tx * 4] = o;
        }
        __syncthreads();
        const int w = t >> 6, l = t & 63;
        const int c   = w * 8 + (l >> 3);     // out row (src col), 0..63
        const int rb0 = (l & 7) * 8;
#pragma unroll
        for (int q = 0; q < 4; ++q) {
            int rb = rb0 + 64 * q;
            bf16x8 o;
#pragma unroll
            for (int j = 0; j < 8; ++j) o[j] = tile[rb + j][c];
            *(bf16x8*)&dst[(size_t)(c0 + c) * R + r0 + rb] = o;
        }
        return;
    }
    // gating + x-cast: 8 tokens per 512-thread block (1 wave per token)
    int n = (bx - 4096) * 8 + (t >> 6);
    int lane = t & 63;
    const float* xr = x + (size_t)n * DIM;
    double acc[NE];
#pragma unroll
    for (int e = 0; e < NE; ++e) acc[e] = 0.0;
#pragma unroll
    for (int i = 0; i < 4; ++i) {
        int d0 = i * 256 + lane * 4;
        float4 v = *(const float4*)&xr[d0];
        bf16x4 o;
        o[0] = (__bf16)v.x; o[1] = (__bf16)v.y; o[2] = (__bf16)v.z; o[3] = (__bf16)v.w;
        *(bf16x4*)&xb[(size_t)n * DIM + d0] = o;
        const float* wr = wg + (size_t)d0 * NE;
#pragma unroll
        for (int j = 0; j < 4; ++j) {
            double xv = (double)((&v.x)[j]);
#pragma unroll
            for (int e = 0; e < NE; ++e) acc[e] += xv * (double)wr[j * NE + e];
        }
    }
#pragma unroll
    for (int e = 0; e < NE; ++e)
        for (int off = 32; off > 0; off >>= 1) acc[e] += __shfl_xor(acc[e], off);
    if (lane == 0) {
        int i0 = 0; double v0 = acc[0];
#pragma unroll
        for (int e = 1; e < NE; ++e) if (acc[e] > v0) { v0 = acc[e]; i0 = e; }
        int i1 = -1; double v1 = -1e300;
#pragma unroll
        for (int e = 0; e < NE; ++e) if (e != i0 && acc[e] > v1) { v1 = acc[e]; i1 = e; }
        double e1 = exp(v1 - v0);
        double s = 1.0 + e1;
        float g0 = (float)(1.0 / s), g1 = (float)(e1 / s);
        tki[n*2]   = i0;  tki[n*2+1] = i1;
        tkg[n*2]   = g0;  tkg[n*2+1] = g1;
        atomicAdd(&counts[i0], 1);
        atomicAdd(&counts[i1], 1);
        atomicAdd(&imp[i0], g0);
        atomicAdd(&imp[i1], g1);
    }
}

// ---------------- aux loss + prefix-sum bases ----------------
__global__ void k_finalize(const float* __restrict__ imp, const int* __restrict__ counts,
                           int* __restrict__ bases, float* __restrict__ aux_out) {
    if (threadIdx.x == 0 && blockIdx.x == 0) {
        float m = 0.f;
        for (int e = 0; e < NE; ++e) m += imp[e];
        m /= (float)NE;
        float var = 0.f;
        for (int e = 0; e < NE; ++e) { float d = imp[e] - m; var += d * d; }
        var /= (float)NE;
        aux_out[0] = 0.01f * var / (m * m + 1e-10f);
        int b = 0;
        for (int e = 0; e < NE; ++e) { bases[e] = b; b += counts[e]; }
    }
}

// ---------------- build per-expert token lists + inverse slot map ----------------
__global__ void k_build(const int* __restrict__ tki,
                        const int* __restrict__ bases, int* __restrict__ cursor,
                        int* __restrict__ tok_ids, int* __restrict__ slotmap) {
    int i = blockIdx.x * 256 + threadIdx.x;
    if (i < SLOTS) {
        int e = tki[i];
        int p = atomicAdd(&cursor[e], 1);
        int s = bases[e] + p;
        tok_ids[s] = i >> 1;
        slotmap[i] = s;
    }
}

// ====== grouped GEMM, 256x256 tile, BK=32, 8 waves (2M x 4N), per-wave 128x64 ======
// (verbatim from R12 — passing, ~100 us each)
template <int MODE>
__global__ __launch_bounds__(512, 2)
void k_gemm(const bf16_t* __restrict__ A,    // MODE0: xb [N][DIM]; MODE1: hbuf [SLOTS][HID]
            const bf16_t* __restrict__ Bt,   // MODE0: w1t [E][HID][DIM]; MODE1: w2t [E][OUTD][HID]
            const float* __restrict__ bias,
            const int* __restrict__ tok_ids,
            const int* __restrict__ bases,
            const int* __restrict__ counts,
            bf16_t* __restrict__ Y) {
    constexpr int KD   = (MODE == 0) ? DIM : HID;
    constexpr int ND   = (MODE == 0) ? HID : OUTD;
    constexpr int KLEN = (MODE == 0) ? DIM : (HID / 2);   // 1024 / 2048
    constexpr int KT   = KLEN / 32;                       // 32 / 64
    constexpr int BUFE = 16384;               // elems per buffer (A 8192 + B 8192 = 32 KiB)

    const int e  = blockIdx.x & 7;            // expert pinned to XCD
    const int lb = blockIdx.x >> 3;           // 0..31
    const int ne = counts[e];
    if (ne == 0) return;
    const int b0 = bases[e];
    const int NTy = (ne + 255) >> 8;
    const int NTILES = (MODE == 0) ? (16 * NTy) : (8 * NTy);

    extern __shared__ bf16_t lds[];           // 3 * BUFE elems = 96 KiB

    const int t = threadIdx.x, w = t >> 6, L = t & 63;
    const int wm = w >> 2, wn = w & 3;        // 2M x 4N; per-wave out 128x64
    const int lr = L & 15, lq = L >> 4;
    const int srow  = L >> 2;                 // staging row-local (16 rows per GLL)
    const int sslot = L & 3;                  // 16B chunk

    int offA[8], offB[4];
#pragma unroll
    for (int i = 0; i < 8; ++i) {
        int r = wm * 128 + i * 16 + lr;
        offA[i] = r * 32 + ((lq ^ ((r >> 1) & 3)) << 3);
    }
#pragma unroll
    for (int j = 0; j < 4; ++j) {
        int r = wn * 64 + j * 16 + lr;
        offB[j] = 8192 + r * 32 + ((lq ^ ((r >> 1) & 3)) << 3);
    }
    int sdstA[2], sdstB[2];
#pragma unroll
    for (int g = 0; g < 2; ++g) {
        sdstA[g] = (g * 128 + w * 16) * 32;
        sdstB[g] = 8192 + (g * 128 + w * 16) * 32;
    }

#define GLL(srcp, dste) __builtin_amdgcn_global_load_lds( \
        (const __attribute__((address_space(1))) uint32_t*)(srcp), \
        (__attribute__((address_space(3))) uint32_t*)(lds + (dste)), 16, 0, 0)
#define STAGE(Tt, bsl) { \
        _Pragma("unroll") for (int g_ = 0; g_ < 2; ++g_) { \
            GLL(aptr[g_] + (Tt) * 32, (bsl) * BUFE + sdstA[g_]); \
            GLL(bptr[g_] + (Tt) * 32, (bsl) * BUFE + sdstB[g_]); } }

    for (int ti = lb; ti < NTILES; ti += 32) {
        int panel = ti / NTy, y = ti - panel * NTy, kslot = 0;
        if (MODE == 1) { kslot = panel & 1; panel >>= 1; }
        const int m0 = y * 256, n0 = panel * 256;
        const int koff = (MODE == 0) ? 0 : kslot * KLEN;
        bf16_t* __restrict__ Yw = (MODE == 0) ? Y : (Y + (size_t)kslot * SLOTS * OUTD);

        const bf16_t* aptr[2];
        const bf16_t* bptr[2];
#pragma unroll
        for (int g = 0; g < 2; ++g) {
            int row = g * 128 + w * 16 + srow;
            int gk  = sslot ^ ((row >> 1) & 3);
            int mm = m0 + row;
            int rr = (mm < ne) ? mm : (ne - 1);
            size_t arow = (MODE == 0) ? (size_t)tok_ids[b0 + rr] * KD : (size_t)(b0 + rr) * KD;
            aptr[g] = A + arow + koff + gk * 8;
            bptr[g] = Bt + ((size_t)e * ND + n0 + row) * KD + koff + gk * 8;
        }

        f32x4 acc[8][4];
#pragma unroll
        for (int i = 0; i < 8; ++i)
#pragma unroll
            for (int j = 0; j < 4; ++j) acc[i][j] = (f32x4){0.f, 0.f, 0.f, 0.f};

        // cover previous tile's last-iteration LDS reads before overwriting buf0/buf1
        __builtin_amdgcn_s_barrier();

        STAGE(0, 0); STAGE(1, 1);

        int cb = 0;
        int nb = 2;
        for (int T = 0; T < KT; ++T) {
            if (T < KT - 1) { asm volatile("s_waitcnt vmcnt(4)" ::: "memory"); }
            else            { asm volatile("s_waitcnt vmcnt(0)" ::: "memory"); }
            __builtin_amdgcn_s_barrier();
            if (T + 2 < KT) STAGE(T + 2, nb);

            bf16x8 fb[4], fa[8];
#pragma unroll
            for (int j = 0; j < 4; ++j) fb[j] = *(const bf16x8*)(lds + cb * BUFE + offB[j]);
#pragma unroll
            for (int i = 0; i < 4; ++i) fa[i] = *(const bf16x8*)(lds + cb * BUFE + offA[i]);
            __builtin_amdgcn_sched_barrier(0);
#pragma unroll
            for (int i = 4; i < 8; ++i) fa[i] = *(const bf16x8*)(lds + cb * BUFE + offA[i]);
            __builtin_amdgcn_sched_barrier(0);
            asm volatile("s_waitcnt lgkmcnt(4)" ::: "memory");   // fb + fa0-3 done
            __builtin_amdgcn_sched_barrier(0);
            __builtin_amdgcn_s_setprio(1);
#pragma unroll
            for (int i = 0; i < 4; ++i)
#pragma unroll
                for (int j = 0; j < 4; ++j)
                    acc[i][j] = __builtin_amdgcn_mfma_f32_16x16x32_bf16(fb[j], fa[i], acc[i][j], 0, 0, 0);
            __builtin_amdgcn_s_setprio(0);
            asm volatile("s_waitcnt lgkmcnt(0)" ::: "memory");   // fa4-7 done (hidden under mh0)
            __builtin_amdgcn_sched_barrier(0);
            __builtin_amdgcn_s_setprio(1);
#pragma unroll
            for (int i = 4; i < 8; ++i)
#pragma unroll
                for (int j = 0; j < 4; ++j)
                    acc[i][j] = __builtin_amdgcn_mfma_f32_16x16x32_bf16(fb[j], fa[i], acc[i][j], 0, 0, 0);
            __builtin_amdgcn_s_setprio(0);

            cb = (cb == 2) ? 0 : cb + 1;
            nb = (nb == 2) ? 0 : nb + 1;
        }

        const int kbias = (MODE == 0) ? 1 : (kslot == 0 ? 1 : 0);
#pragma unroll
        for (int i = 0; i < 8; ++i) {
            int gm = m0 + wm * 128 + i * 16 + lr;
            if (gm < ne) {
#pragma unroll
                for (int j = 0; j < 4; ++j) {
                    int gn = n0 + wn * 64 + j * 16 + lq * 4;
                    f32x4 bv = *(const f32x4*)&bias[(size_t)e * ND + gn];
                    bf16x4 hv;
#pragma unroll
                    for (int r = 0; r < 4; ++r) {
                        float v = acc[i][j][r];
                        if (kbias) v += bv[r];
                        if (MODE == 0) v = fmaxf(v, 0.f);
                        hv[r] = (__bf16)v;
                    }
                    *(bf16x4*)&Yw[(size_t)(b0 + gm) * ND + gn] = hv;
                }
            }
        }
    }
#undef STAGE
#undef GLL
}

// ---------------- combine: out[n] = g0*(y0a+y0b) + g1*(y1a+y1b) (fp32) ----------------
__global__ void k_combine(const bf16_t* __restrict__ ybuf,   // [2][SLOTS][OUTD]
                          const int* __restrict__ slotmap,
                          const float* __restrict__ tkg,
                          float* __restrict__ out) {
    int n = blockIdx.x;
    int d = threadIdx.x * 4;
    int s0 = slotmap[2 * n], s1 = slotmap[2 * n + 1];
    float g0 = tkg[2 * n],  g1 = tkg[2 * n + 1];
    const bf16_t* y2 = ybuf + (size_t)SLOTS * OUTD;
    bf16x4 a0 = *(const bf16x4*)&ybuf[(size_t)s0 * OUTD + d];
    bf16x4 a1 = *(const bf16x4*)&y2  [(size_t)s0 * OUTD + d];
    bf16x4 c0 = *(const bf16x4*)&ybuf[(size_t)s1 * OUTD + d];
    bf16x4 c1 = *(const bf16x4*)&y2  [(size_t)s1 * OUTD + d];
    f32x4 o;
#pragma unroll
    for (int r = 0; r < 4; ++r)
        o[r] = g0 * ((float)a0[r] + (float)a1[r]) + g1 * ((float)c0[r] + (float)c1[r]);
    *(f32x4*)&out[(size_t)n * OUTD + d] = o;
}

extern "C" void kernel_launch(void* const* d_in, const int* in_sizes, int n_in,
                              void* d_out, int out_size, void* d_ws, size_t ws_size,
                              hipStream_t stream) {
    const float* x  = (const float*)d_in[0];
    const float* wg = (const float*)d_in[1];
    const float* w1 = (const float*)d_in[2];
    const float* b1 = (const float*)d_in[3];
    const float* w2 = (const float*)d_in[4];
    const float* b2 = (const float*)d_in[5];
    float* out = (float*)d_out;

    char* ws = (char*)d_ws;
    size_t o = 0;
    auto alloc = [&](size_t b) { size_t r = o; o = (o + b + 255) & ~(size_t)255; return r; };
    int*    counts  = (int*)(ws + alloc(NE * 4));
    int*    cursor  = (int*)(ws + alloc(NE * 4));
    int*    bases   = (int*)(ws + alloc(NE * 4));
    float*  imp     = (float*)(ws + alloc(NE * 4));
    int*    tki     = (int*)(ws + alloc(SLOTS * 4));
    float*  tkg     = (float*)(ws + alloc(SLOTS * 4));
    int*    tok_ids = (int*)(ws + alloc(SLOTS * 4));
    int*    slotmap = (int*)(ws + alloc(SLOTS * 4));
    bf16_t* xb      = (bf16_t*)(ws + alloc((size_t)N_TOK * DIM * 2));
    size_t  w1t_off = alloc((size_t)NE * HID * DIM * 2);
    bf16_t* w1t     = (bf16_t*)(ws + w1t_off);
    bf16_t* ybuf    = (bf16_t*)(ws + w1t_off);   // [2][SLOTS][OUTD] aliases w1t (dead after GEMM-1)
    bf16_t* w2t     = (bf16_t*)(ws + alloc((size_t)NE * OUTD * HID * 2));
    bf16_t* hbuf    = (bf16_t*)(ws + alloc((size_t)SLOTS * HID * 2));
    (void)ws_size; (void)n_in; (void)in_sizes;

    hipFuncSetAttribute((const void*)&k_gemm<0>, hipFuncAttributeMaxDynamicSharedMemorySize, 98304);
    hipFuncSetAttribute((const void*)&k_gemm<1>, hipFuncAttributeMaxDynamicSharedMemorySize, 98304);

    hipMemsetAsync(ws, 0, 1024, stream);   // counts + cursor + bases + imp

    // mega prep: 2048 w1-T + 2048 w2-T (256x64 tiles) + 512 gating blocks (8 tok each)
    k_prep<<<4096 + 512, 512, 0, stream>>>(x, wg, w1, w2, xb, w1t, w2t,
                                           tki, tkg, counts, imp);
    k_finalize<<<1, 64, 0, stream>>>(imp, counts, bases, out + (size_t)N_TOK * OUTD);
    k_build<<<SLOTS / 256, 256, 0, stream>>>(tki, bases, cursor, tok_ids, slotmap);

    // 256 blocks = 8 XCD-pinned experts x 32 worklist slots; 96 KiB dynamic LDS
    k_gemm<0><<<256, 512, 98304, stream>>>(xb, w1t, b1, tok_ids, bases, counts, hbuf);
    k_gemm<1><<<256, 512, 98304, stream>>>(hbuf, w2t, b2, tok_ids, bases, counts, ybuf);

    k_combine<<<N_TOK, 256, 0, stream>>>(ybuf, slotmap, tkg, out);
}